// Round 1
// baseline (2553.910 us; speedup 1.0000x reference)
//
#include <hip/hip_runtime.h>

// ---------------------------------------------------------------------------
// E2E seq2seq: encoder (Linear+ReLU) -> 64-step attention-GRU decoder ->
// logits GEMM [4096x128]x[128x32000] + log_softmax.
//
// Structure:
//   K1  transpose weights (coalesced GEMV layouts), convert Wout -> fp16
//   K2  encoder: enc_out [S,B,E], uh [S,B,A]  (f32, ws)
//   K3  decode: 64 WGs (one per batch lane), T=64 sequential steps,
//       enc_out/uh for that lane pinned in LDS (139 KB dynamic), h in LDS.
//       Writes h_t as fp16 -> Hf [4096,128].
//   K4  logits pass1 (MFMA fp16): per-row-block online-softmax partials
//   K5  reduce partials -> L[row] = max + log(sumexp)
//   K6  logits pass2 (MFMA fp16): recompute tile, write x - L[row] (524 MB)
// ---------------------------------------------------------------------------

typedef _Float16 half8 __attribute__((ext_vector_type(8)));
typedef float floatx4 __attribute__((ext_vector_type(4)));

__device__ __forceinline__ float fast_tanh(float x) {
  float e = __expf(2.0f * x);
  return 1.0f - 2.0f / (e + 1.0f);   // saturates correctly when e -> inf / 0
}
__device__ __forceinline__ float fast_sigmoid(float x) {
  return 1.0f / (1.0f + __expf(-x));
}

// ---------------- prep kernels ----------------
__global__ void transpose_kernel(const float* __restrict__ src,
                                 float* __restrict__ dst, int R, int C) {
  int i = blockIdx.x * 256 + threadIdx.x;
  if (i < R * C) {
    int r = i / C, c = i - r * C;
    dst[c * R + r] = src[i];
  }
}

__global__ void cvt_f16_kernel(const float* __restrict__ src,
                               _Float16* __restrict__ dst, int n) {
  int i = blockIdx.x * 256 + threadIdx.x;
  if (i < n) dst[i] = (_Float16)src[i];
}

// ---------------- encoder ----------------
// grid 8192 (= s*64+b), 128 threads. eo_ws/uh_ws layout: [(s*64+b)][128]
__global__ __launch_bounds__(128) void encoder_kernel(
    const float* __restrict__ emb, const float* __restrict__ WeT,
    const float* __restrict__ b_enc, const float* __restrict__ UwT,
    const float* __restrict__ U_b, const int* __restrict__ batch_x,
    float* __restrict__ eo_ws, float* __restrict__ uh_ws) {
  __shared__ float x[128];
  __shared__ float row[128];
  int idx = blockIdx.x;
  int tid = threadIdx.x;
  int id = batch_x[idx];
  x[tid] = emb[id * 128 + tid];
  __syncthreads();
  float acc = b_enc[tid];
#pragma unroll 4
  for (int d = 0; d < 128; ++d) acc += WeT[d * 128 + tid] * x[d];
  acc = fmaxf(acc, 0.0f);
  row[tid] = acc;
  eo_ws[idx * 128 + tid] = acc;
  __syncthreads();
  float a2 = U_b[tid];
#pragma unroll 4
  for (int e = 0; e < 128; ++e) a2 += UwT[e * 128 + tid] * row[e];
  uh_ws[idx * 128 + tid] = a2;
}

// ---------------- decoder ----------------
// 64 WGs (one per batch lane b), 256 threads, dynamic LDS 139280 B.
__global__ __launch_bounds__(256) void decode_kernel(
    const float* __restrict__ emb, const float* __restrict__ WwT,
    const float* __restrict__ Wb, const float* __restrict__ vw,
    const float* __restrict__ vb, const float* __restrict__ WcT,
    const float* __restrict__ Wcb, const float* __restrict__ WihT,
    const float* __restrict__ bih, const float* __restrict__ WhhT,
    const float* __restrict__ bhh, const int* __restrict__ batch_y,
    const float* __restrict__ eo_ws, const float* __restrict__ uh_ws,
    _Float16* __restrict__ Hf) {
  extern __shared__ float sm[];
  float* eo  = sm;                 // 128*129 (pad stride 129: conflict-free)
  float* uhs = eo + 128 * 129;     // 128*129
  float* h   = uhs + 128 * 129;    // 128
  float* wq  = h + 128;            // 128
  float* sc  = wq + 128;           // 128
  float* ctx = sc + 128;           // 128
  float* py  = ctx + 128;          // 128
  float* rnn = py + 128;           // 128
  float* gi  = rnn + 128;          // 384
  float* gh  = gi + 384;           // 384
  float* red = gh + 384;           // 256
  float* scal = red + 256;         // 4

  const int tid = threadIdx.x;
  const int b = blockIdx.x;

  for (int i = tid; i < 128 * 128; i += 256) {
    int s = i >> 7, e = i & 127;
    eo[s * 129 + e]  = eo_ws[(s * 64 + b) * 128 + e];
    uhs[s * 129 + e] = uh_ws[(s * 64 + b) * 128 + e];
  }
  __syncthreads();
  if (tid < 128) {   // h0 = sum_s enc_out
    float a = 0.f;
    for (int s = 0; s < 128; ++s) a += eo[s * 129 + tid];
    h[tid] = a;
  }
  __syncthreads();

  for (int t = 0; t < 64; ++t) {
    // prev_y embedding + wq partials (both only read h / global)
    if (tid < 128) {
      int pid = (t == 0) ? (50000 - 1) : batch_y[(t - 1) * 64 + b];
      py[tid] = emb[pid * 128 + tid];
    }
    {
      int a = tid & 127, hh = tid >> 7;
      int e0 = hh << 6;
      float a0 = 0.f, a1 = 0.f, a2 = 0.f, a3 = 0.f;
      for (int e = e0; e < e0 + 64; e += 4) {
        a0 += WwT[e * 128 + a] * h[e];
        a1 += WwT[(e + 1) * 128 + a] * h[e + 1];
        a2 += WwT[(e + 2) * 128 + a] * h[e + 2];
        a3 += WwT[(e + 3) * 128 + a] * h[e + 3];
      }
      red[tid] = (a0 + a1) + (a2 + a3);
    }
    __syncthreads();
    if (tid < 128) wq[tid] = red[tid] + red[tid + 128] + Wb[tid];
    __syncthreads();
    // scores[s] = sum_a v[a]*tanh(wq[a]+uh[s,a])
    {
      int s = tid & 127, hh = tid >> 7;
      int a0i = hh << 6;
      const float* ur = uhs + s * 129;
      float acc = 0.f;
      for (int a = a0i; a < a0i + 64; ++a)
        acc += vw[a] * fast_tanh(wq[a] + ur[a]);
      red[tid] = acc;
    }
    __syncthreads();
    if (tid < 128) sc[tid] = red[tid] + red[tid + 128] + vb[0];
    __syncthreads();
    // softmax over s (wave 0 only, butterfly shuffles)
    if (tid < 64) {
      float m = fmaxf(sc[tid], sc[tid + 64]);
      for (int o = 32; o >= 1; o >>= 1) m = fmaxf(m, __shfl_xor(m, o, 64));
      float e0_ = __expf(sc[tid] - m);
      float e1_ = __expf(sc[tid + 64] - m);
      sc[tid] = e0_; sc[tid + 64] = e1_;
      float ss = e0_ + e1_;
      for (int o = 32; o >= 1; o >>= 1) ss += __shfl_xor(ss, o, 64);
      if (tid == 0) scal[0] = 1.0f / ss;
    }
    __syncthreads();
    // ctx[e] = (1/sum) * sum_s w[s]*eo[s,e]
    {
      int e = tid & 127, hh = tid >> 7;
      int s0 = hh << 6;
      float a0 = 0.f, a1 = 0.f;
      for (int s = s0; s < s0 + 64; s += 2) {
        a0 += sc[s] * eo[s * 129 + e];
        a1 += sc[s + 1] * eo[(s + 1) * 129 + e];
      }
      red[tid] = a0 + a1;
    }
    __syncthreads();
    if (tid < 128) ctx[tid] = (red[tid] + red[tid + 128]) * scal[0];
    __syncthreads();
    // rnn_in[j] = Wc_b[j] + Wc[:, :128]@py + Wc[:, 128:]@ctx
    {
      int j = tid & 127, hh = tid >> 7;
      const float* src = hh ? ctx : py;
      int ib = hh << 7;
      float a0 = 0.f, a1 = 0.f, a2 = 0.f, a3 = 0.f;
      for (int i2 = 0; i2 < 128; i2 += 4) {
        a0 += WcT[(ib + i2) * 128 + j] * src[i2];
        a1 += WcT[(ib + i2 + 1) * 128 + j] * src[i2 + 1];
        a2 += WcT[(ib + i2 + 2) * 128 + j] * src[i2 + 2];
        a3 += WcT[(ib + i2 + 3) * 128 + j] * src[i2 + 3];
      }
      red[tid] = (a0 + a1) + (a2 + a3);
    }
    __syncthreads();
    if (tid < 128) rnn[tid] = red[tid] + red[tid + 128] + Wcb[tid];
    __syncthreads();
    // GRU gate pre-activations
    for (int g = tid; g < 384; g += 256) {
      float a0 = 0.f, a1 = 0.f, a2 = 0.f, a3 = 0.f;
      for (int j = 0; j < 128; j += 4) {
        a0 += WihT[j * 384 + g] * rnn[j];
        a1 += WihT[(j + 1) * 384 + g] * rnn[j + 1];
        a2 += WihT[(j + 2) * 384 + g] * rnn[j + 2];
        a3 += WihT[(j + 3) * 384 + g] * rnn[j + 3];
      }
      gi[g] = (a0 + a1) + (a2 + a3) + bih[g];
    }
    for (int g = tid; g < 384; g += 256) {
      float a0 = 0.f, a1 = 0.f, a2 = 0.f, a3 = 0.f;
      for (int j = 0; j < 128; j += 4) {
        a0 += WhhT[j * 384 + g] * h[j];
        a1 += WhhT[(j + 1) * 384 + g] * h[j + 1];
        a2 += WhhT[(j + 2) * 384 + g] * h[j + 2];
        a3 += WhhT[(j + 3) * 384 + g] * h[j + 3];
      }
      gh[g] = (a0 + a1) + (a2 + a3) + bhh[g];
    }
    __syncthreads();
    if (tid < 128) {
      float r = fast_sigmoid(gi[tid] + gh[tid]);
      float z = fast_sigmoid(gi[tid + 128] + gh[tid + 128]);
      float ng = fast_tanh(gi[tid + 256] + r * gh[tid + 256]);
      float hn = (1.f - z) * ng + z * h[tid];
      h[tid] = hn;
      Hf[(t * 64 + b) * 128 + tid] = (_Float16)hn;
    }
    __syncthreads();
  }
}

// ---------------- logits GEMM (fp16 MFMA) ----------------
// grid (250, 32), 256 threads; 128x128 C-tile per WG; K=128.
// LDS: A-tile + B-tile, fp16, row stride 136 (2-way conflicts only).
// PASS 1: per-row (max, sumexp) partials over this 128-col block.
// PASS 2: out[row][col] = x - L[row].
template <int PASS>
__global__ __launch_bounds__(256) void logits_kernel(
    const _Float16* __restrict__ Ah,   // [4096][128]
    const _Float16* __restrict__ Bh,   // [32000][128] (Wout rows, K-major)
    const float* __restrict__ bout, const float* __restrict__ Lrow,
    float* __restrict__ pmax, float* __restrict__ psum,
    float* __restrict__ out) {
  extern __shared__ char smem_raw[];
  _Float16* At = (_Float16*)smem_raw;                 // 128*136
  _Float16* Bt = (_Float16*)(smem_raw + 128 * 136 * 2);

  const int nb = blockIdx.x;   // 0..249
  const int mb = blockIdx.y;   // 0..31
  const int tid = threadIdx.x;
  const int lane = tid & 63;
  const int wid = tid >> 6;
  const int m0 = mb * 128, n0 = nb * 128;

  const uint4* Ag = (const uint4*)(Ah + (size_t)m0 * 128);
  const uint4* Bg = (const uint4*)(Bh + (size_t)n0 * 128);
  for (int i = tid; i < 2048; i += 256) {
    int r = i >> 4, c = i & 15;
    *(uint4*)(At + r * 136 + c * 8) = Ag[r * 16 + c];
    *(uint4*)(Bt + r * 136 + c * 8) = Bg[r * 16 + c];
  }
  __syncthreads();

  const int wm = wid >> 1, wn = wid & 1;
  const int lr = lane & 15;
  const int quad = lane >> 4;

  floatx4 acc[4][4];
  const floatx4 z4 = {0.f, 0.f, 0.f, 0.f};
  for (int i = 0; i < 4; ++i)
    for (int j = 0; j < 4; ++j) acc[i][j] = z4;

  for (int kk = 0; kk < 4; ++kk) {
    int kof = kk * 32 + quad * 8;
    half8 af[4], bfr[4];
#pragma unroll
    for (int ms = 0; ms < 4; ++ms)
      af[ms] = *(const half8*)(At + (wm * 64 + ms * 16 + lr) * 136 + kof);
#pragma unroll
    for (int ns = 0; ns < 4; ++ns)
      bfr[ns] = *(const half8*)(Bt + (wn * 64 + ns * 16 + lr) * 136 + kof);
#pragma unroll
    for (int ms = 0; ms < 4; ++ms)
#pragma unroll
      for (int ns = 0; ns < 4; ++ns)
        acc[ms][ns] = __builtin_amdgcn_mfma_f32_16x16x32_f16(
            af[ms], bfr[ns], acc[ms][ns], 0, 0, 0);
  }

  float bcol[4];
#pragma unroll
  for (int ns = 0; ns < 4; ++ns)
    bcol[ns] = bout[n0 + wn * 64 + ns * 16 + lr];

  if (PASS == 1) {
    __syncthreads();   // done with tiles; reuse LDS for reductions
    float* red_m = (float*)smem_raw;   // [2][128]
    float* red_s = red_m + 256;        // [2][128]
#pragma unroll
    for (int ms = 0; ms < 4; ++ms) {
#pragma unroll
      for (int r = 0; r < 4; ++r) {
        float v0 = acc[ms][0][r] + bcol[0];
        float v1 = acc[ms][1][r] + bcol[1];
        float v2 = acc[ms][2][r] + bcol[2];
        float v3 = acc[ms][3][r] + bcol[3];
        float vmax = fmaxf(fmaxf(v0, v1), fmaxf(v2, v3));
        for (int o = 1; o < 16; o <<= 1)
          vmax = fmaxf(vmax, __shfl_xor(vmax, o, 16));
        float s = __expf(v0 - vmax) + __expf(v1 - vmax) +
                  __expf(v2 - vmax) + __expf(v3 - vmax);
        for (int o = 1; o < 16; o <<= 1) s += __shfl_xor(s, o, 16);
        if (lr == 0) {
          int row = wm * 64 + ms * 16 + quad * 4 + r;
          red_m[wn * 128 + row] = vmax;
          red_s[wn * 128 + row] = s;
        }
      }
    }
    __syncthreads();
    if (tid < 128) {
      float ma = red_m[tid], mb2 = red_m[128 + tid];
      float M = fmaxf(ma, mb2);
      float S = red_s[tid] * __expf(ma - M) + red_s[128 + tid] * __expf(mb2 - M);
      pmax[(size_t)(m0 + tid) * 250 + nb] = M;
      psum[(size_t)(m0 + tid) * 250 + nb] = S;
    }
  } else {
#pragma unroll
    for (int ms = 0; ms < 4; ++ms) {
#pragma unroll
      for (int r = 0; r < 4; ++r) {
        int grow = m0 + wm * 64 + ms * 16 + quad * 4 + r;
        float L = Lrow[grow];
        float* orow = out + (size_t)grow * 32000 + n0 + wn * 64 + lr;
#pragma unroll
        for (int ns = 0; ns < 4; ++ns)
          orow[ns * 16] = acc[ms][ns][r] + bcol[ns] - L;
      }
    }
  }
}

__global__ void reduce_l_kernel(const float* __restrict__ pmax,
                                const float* __restrict__ psum,
                                float* __restrict__ Lrow) {
  int row = blockIdx.x * 256 + threadIdx.x;
  if (row >= 4096) return;
  const float* pm = pmax + (size_t)row * 250;
  const float* ps = psum + (size_t)row * 250;
  float M = -1e30f;
  for (int i = 0; i < 250; ++i) M = fmaxf(M, pm[i]);
  float S = 0.f;
  for (int i = 0; i < 250; ++i) S += ps[i] * __expf(pm[i] - M);
  Lrow[row] = M + logf(S);
}

// ---------------------------------------------------------------------------
extern "C" void kernel_launch(void* const* d_in, const int* in_sizes, int n_in,
                              void* d_out, int out_size, void* d_ws,
                              size_t ws_size, hipStream_t stream) {
  const float* emb   = (const float*)d_in[0];
  const float* W_enc = (const float*)d_in[1];
  const float* b_enc = (const float*)d_in[2];
  const float* U_w   = (const float*)d_in[3];
  const float* U_b   = (const float*)d_in[4];
  const float* Ww    = (const float*)d_in[5];
  const float* Wb    = (const float*)d_in[6];
  const float* v_w   = (const float*)d_in[7];
  const float* v_b   = (const float*)d_in[8];
  const float* Wc_w  = (const float*)d_in[9];
  const float* Wc_b  = (const float*)d_in[10];
  const float* Wih   = (const float*)d_in[11];
  const float* bih   = (const float*)d_in[12];
  const float* Whh   = (const float*)d_in[13];
  const float* bhh   = (const float*)d_in[14];
  const float* Wout  = (const float*)d_in[15];
  const float* bout  = (const float*)d_in[16];
  const int* batch_x = (const int*)d_in[17];
  const int* batch_y = (const int*)d_in[18];
  float* out = (float*)d_out;

  char* w = (char*)d_ws;
  size_t off = 0;
  auto alloc = [&](size_t bytes) {
    void* p = w + off;
    off += (bytes + 255) & ~(size_t)255;
    return p;
  };
  float* eo_ws = (float*)alloc(128 * 64 * 128 * 4);
  float* uh_ws = (float*)alloc(128 * 64 * 128 * 4);
  float* WeT   = (float*)alloc(128 * 128 * 4);
  float* UwT   = (float*)alloc(128 * 128 * 4);
  float* WwT   = (float*)alloc(128 * 128 * 4);
  float* WcT   = (float*)alloc(256 * 128 * 4);
  float* WihT  = (float*)alloc(128 * 384 * 4);
  float* WhhT  = (float*)alloc(128 * 384 * 4);
  _Float16* Hf  = (_Float16*)alloc(4096 * 128 * 2);
  _Float16* WoH = (_Float16*)alloc((size_t)32000 * 128 * 2);
  float* pmax = (float*)alloc((size_t)4096 * 250 * 4);
  float* psum = (float*)alloc((size_t)4096 * 250 * 4);
  float* Lrow = (float*)alloc(4096 * 4);
  (void)ws_size; (void)in_sizes; (void)n_in; (void)out_size;

  // opt-in >64KB dynamic LDS (idempotent; not a stream op)
  const int DEC_SH = (2 * 128 * 129 + 6 * 128 + 2 * 384 + 256 + 4) * 4; // 139280
  const int P3_SH = 2 * 128 * 136 * 2;                                  // 69632
  hipFuncSetAttribute((const void*)decode_kernel,
                      hipFuncAttributeMaxDynamicSharedMemorySize, DEC_SH);
  hipFuncSetAttribute((const void*)(logits_kernel<1>),
                      hipFuncAttributeMaxDynamicSharedMemorySize, P3_SH);
  hipFuncSetAttribute((const void*)(logits_kernel<2>),
                      hipFuncAttributeMaxDynamicSharedMemorySize, P3_SH);

  // prep: transposes + fp16 convert
  transpose_kernel<<<(128 * 128 + 255) / 256, 256, 0, stream>>>(W_enc, WeT, 128, 128);
  transpose_kernel<<<(128 * 128 + 255) / 256, 256, 0, stream>>>(U_w, UwT, 128, 128);
  transpose_kernel<<<(128 * 128 + 255) / 256, 256, 0, stream>>>(Ww, WwT, 128, 128);
  transpose_kernel<<<(128 * 256 + 255) / 256, 256, 0, stream>>>(Wc_w, WcT, 128, 256);
  transpose_kernel<<<(384 * 128 + 255) / 256, 256, 0, stream>>>(Wih, WihT, 384, 128);
  transpose_kernel<<<(384 * 128 + 255) / 256, 256, 0, stream>>>(Whh, WhhT, 384, 128);
  cvt_f16_kernel<<<(32000 * 128 + 255) / 256, 256, 0, stream>>>(Wout, WoH, 32000 * 128);

  encoder_kernel<<<128 * 64, 128, 0, stream>>>(emb, WeT, b_enc, UwT, U_b,
                                               batch_x, eo_ws, uh_ws);

  decode_kernel<<<64, 256, DEC_SH, stream>>>(emb, WwT, Wb, v_w, v_b, WcT, Wc_b,
                                             WihT, bih, WhhT, bhh, batch_y,
                                             eo_ws, uh_ws, Hf);

  dim3 g3(250, 32);
  logits_kernel<1><<<g3, 256, P3_SH, stream>>>(Hf, WoH, bout, nullptr, pmax,
                                               psum, nullptr);
  reduce_l_kernel<<<16, 256, 0, stream>>>(pmax, psum, Lrow);
  logits_kernel<2><<<g3, 256, P3_SH, stream>>>(Hf, WoH, bout, Lrow, nullptr,
                                               nullptr, out);
}